// Round 1
// baseline (658.088 us; speedup 1.0000x reference)
//
#include <hip/hip_runtime.h>
#include <hip/hip_bf16.h>
#include <stdint.h>

#define B2 8192
#define D  512
#define K2 2048        // [A_hi(1024) | A_lo(1024)] vs [B(1024) | B(1024)]
#define NM1 (B2 - 1)   // 8191

typedef _Float16 f16;
typedef _Float16 f16x8 __attribute__((ext_vector_type(8)));
typedef float    f32x4 __attribute__((ext_vector_type(4)));

// ---------------------------------------------------------------------------
// prep_rows: per row j build split-fp16 GEMM operands, t3[j], ls[j], zero rowsum
//   A row: [hi(x^2) | hi(x) | lo(x^2) | lo(x)]
//   B row: [h(inv)  | h(-2x*inv) | h(inv) | h(-2x*inv)]   (B duplicated for 2-product split)
// ---------------------------------------------------------------------------
__global__ __launch_bounds__(256) void prep_rows(
    const float* __restrict__ feat, const float* __restrict__ sig,
    f16* __restrict__ Ahat, f16* __restrict__ Bhat,
    float* __restrict__ t3, float* __restrict__ ls, float* __restrict__ rowsum)
{
    int j = blockIdx.x;
    int t = threadIdx.x;
    const float* xr = feat + (size_t)j * D;
    const float* sr = sig  + (size_t)j * D;
    f16* Ar = Ahat + (size_t)j * K2;
    f16* Br = Bhat + (size_t)j * K2;
    float t3p = 0.f, lsp = 0.f;
    for (int d = t; d < D; d += 256) {
        float x = xr[d], s = sr[d];
        float inv = 1.0f / s;
        float x2 = x * x;
        f16 a0h = (f16)x2; f16 a0l = (f16)(x2 - (float)a0h);
        f16 a1h = (f16)x;  f16 a1l = (f16)(x  - (float)a1h);
        Ar[d] = a0h; Ar[512 + d] = a1h; Ar[1024 + d] = a0l; Ar[1536 + d] = a1l;
        float b1 = -2.0f * x * inv;
        f16 b0h = (f16)inv; f16 b1h = (f16)b1;
        Br[d] = b0h; Br[512 + d] = b1h; Br[1024 + d] = b0h; Br[1536 + d] = b1h;
        t3p += x2 * inv;
        lsp += __logf(s);
    }
    for (int off = 32; off; off >>= 1) {
        t3p += __shfl_down(t3p, off);
        lsp += __shfl_down(lsp, off);
    }
    __shared__ float wt[4], wl[4];
    int lane = t & 63, w = t >> 6;
    if (lane == 0) { wt[w] = t3p; wl[w] = lsp; }
    __syncthreads();
    if (t == 0) {
        t3[j] = wt[0] + wt[1] + wt[2] + wt[3];
        ls[j] = wl[0] + wl[1] + wl[2] + wl[3];
        rowsum[j] = 0.0f;
    }
}

// ---------------------------------------------------------------------------
// prep_pos: exact fp32 gt[i] = dist(i, pos(i)); fold constants:
//   rowc[i]  = 0.1*gt[i] + 0.5*ls[i]
//   colc2[j] = -0.5*ls[pos(j)] - 0.1*t3[j]
// ---------------------------------------------------------------------------
__global__ __launch_bounds__(256) void prep_pos(
    const float* __restrict__ feat, const float* __restrict__ sig,
    const int* __restrict__ label,
    const float* __restrict__ t3, const float* __restrict__ ls,
    float* __restrict__ rowc, float* __restrict__ colc2)
{
    int i = blockIdx.x;
    int t = threadIdx.x;
    int lb = label[i];
    int p  = lb + (lb >= i ? 1 : 0);
    const float* xi = feat + (size_t)i * D;
    const float* xp = feat + (size_t)p * D;
    const float* sp = sig  + (size_t)p * D;
    float g = 0.f;
    for (int d = t; d < D; d += 256) {
        float dx = xi[d] - xp[d];
        g += dx * dx / sp[d];
    }
    for (int off = 32; off; off >>= 1) g += __shfl_down(g, off);
    __shared__ float wg[4];
    if ((t & 63) == 0) wg[t >> 6] = g;
    __syncthreads();
    if (t == 0) {
        float gt = wg[0] + wg[1] + wg[2] + wg[3];
        rowc[i]  = 0.1f * gt + 0.5f * ls[i];
        colc2[i] = -0.5f * ls[p] - 0.1f * t3[i];
    }
}

// ---------------------------------------------------------------------------
// Fused GEMM (M=N=8192, K=2048, fp16 MFMA 16x16x32) + exp epilogue + row sums.
// 128x128 tile / block, 4 waves in 2x2, each wave 4x4 MFMA tiles.
// BK=64, global_load_lds dwordx4 staging, XOR chunk swizzle (16B chunks).
// ---------------------------------------------------------------------------
__global__ __launch_bounds__(256, 3) void gemm_epilogue(
    const f16* __restrict__ Ahat, const f16* __restrict__ Bhat,
    const float* __restrict__ rowc, const float* __restrict__ colc2,
    float* __restrict__ rowsum, float* __restrict__ out)
{
    __shared__ f16 As[128 * 64];
    __shared__ f16 Bs[128 * 64];
    __shared__ float rS[128], cS[128];

    // swizzle: 8-column panels of the 64x64 block grid
    int bid = blockIdx.x;
    int bn = ((bid >> 9) << 3) + (bid & 7);
    int bm = (bid >> 3) & 63;

    int t = threadIdx.x;
    int l = t & 63, w = t >> 6;
    int wm = (w & 1) * 64, wn = (w >> 1) * 64;

    // staging: thread t covers tile row (t>>3)+32*round, LDS chunk t&7.
    // LDS slot (r, cl) holds global chunk cl ^ (r&7).
    int srow   = t >> 3;                  // 0..31
    int schunk = t & 7;
    int gchunk = schunk ^ (srow & 7);
    const f16* gA = Ahat + (size_t)(bm * 128 + srow) * K2 + gchunk * 8;
    const f16* gB = Bhat + (size_t)(bn * 128 + srow) * K2 + gchunk * 8;

    f32x4 zero4 = {0.f, 0.f, 0.f, 0.f};
    f32x4 acc[4][4];
    #pragma unroll
    for (int a = 0; a < 4; ++a)
        #pragma unroll
        for (int b = 0; b < 4; ++b) acc[a][b] = zero4;

    for (int kb = 0; kb < K2; kb += 64) {
        __syncthreads();   // previous tile fully consumed
        #pragma unroll
        for (int rd = 0; rd < 4; ++rd) {
            __builtin_amdgcn_global_load_lds(
                (const __attribute__((address_space(1))) unsigned int*)(gA + (size_t)rd * 32 * K2 + kb),
                (__attribute__((address_space(3))) unsigned int*)(&As[rd * 2048 + w * 512]),
                16, 0, 0);
            __builtin_amdgcn_global_load_lds(
                (const __attribute__((address_space(1))) unsigned int*)(gB + (size_t)rd * 32 * K2 + kb),
                (__attribute__((address_space(3))) unsigned int*)(&Bs[rd * 2048 + w * 512]),
                16, 0, 0);
        }
        __syncthreads();   // compiler drains vmcnt before barrier

        #pragma unroll
        for (int ks = 0; ks < 2; ++ks) {
            f16x8 af[4], bf[4];
            int cl = (ks * 4 + (l >> 4)) ^ (l & 7);   // swizzled chunk
            #pragma unroll
            for (int mi = 0; mi < 4; ++mi) {
                int ra = wm + mi * 16 + (l & 15);
                af[mi] = *(const f16x8*)&As[ra * 64 + cl * 8];
                int rb = wn + mi * 16 + (l & 15);
                bf[mi] = *(const f16x8*)&Bs[rb * 64 + cl * 8];
            }
            #pragma unroll
            for (int mi = 0; mi < 4; ++mi)
                #pragma unroll
                for (int ni = 0; ni < 4; ++ni)
                    acc[mi][ni] = __builtin_amdgcn_mfma_f32_16x16x32_f16(
                        af[mi], bf[ni], acc[mi][ni], 0, 0, 0);
        }
    }

    // stage per-row/per-col constants
    if (t < 128)      rS[t]       = rowc[bm * 128 + t];
    else              cS[t - 128] = colc2[bn * 128 + (t - 128)];
    __syncthreads();

    int quad = l >> 4, lc = l & 15;
    #pragma unroll
    for (int mi = 0; mi < 4; ++mi) {
        #pragma unroll
        for (int rg = 0; rg < 4; ++rg) {
            int il = wm + mi * 16 + quad * 4 + rg;   // C/D: row = quad*4+reg
            int i  = bm * 128 + il;
            float rc = rS[il];
            float part = 0.f;
            #pragma unroll
            for (int ni = 0; ni < 4; ++ni) {
                int jl = wn + ni * 16 + lc;          // C/D: col = lane&15
                int j  = bn * 128 + jl;
                float v = __expf(rc - 0.1f * acc[mi][ni][rg] + cS[jl]);
                if (j != i) {
                    out[1 + (size_t)i * NM1 + (j - (j > i ? 1 : 0))] = v;
                    part += v;
                }
            }
            // reduce over the 16 lanes holding this row's columns
            part += __shfl_xor(part, 1);
            part += __shfl_xor(part, 2);
            part += __shfl_xor(part, 4);
            part += __shfl_xor(part, 8);
            if (lc == 0) atomicAdd(&rowsum[i], part);
        }
    }
}

// ---------------------------------------------------------------------------
// loss = mean_i log(rowsum[i]) -> out[0]
// ---------------------------------------------------------------------------
__global__ __launch_bounds__(256) void loss_k(const float* __restrict__ rowsum,
                                              float* __restrict__ out)
{
    int t = threadIdx.x;
    float s = 0.f;
    for (int r = t; r < B2; r += 256) s += __logf(rowsum[r]);
    for (int off = 32; off; off >>= 1) s += __shfl_down(s, off);
    __shared__ float wv[4];
    if ((t & 63) == 0) wv[t >> 6] = s;
    __syncthreads();
    if (t == 0) out[0] = (wv[0] + wv[1] + wv[2] + wv[3]) * (1.0f / (float)B2);
}

extern "C" void kernel_launch(void* const* d_in, const int* in_sizes, int n_in,
                              void* d_out, int out_size, void* d_ws, size_t ws_size,
                              hipStream_t stream) {
    const float* feat  = (const float*)d_in[0];
    const float* sig   = (const float*)d_in[1];
    const int*   label = (const int*)d_in[2];
    float* out = (float*)d_out;

    char* ws = (char*)d_ws;
    f16* Ahat = (f16*)ws;                                  // 32 MB
    f16* Bhat = (f16*)(ws + (size_t)B2 * K2 * 2);          // 32 MB
    float* t3     = (float*)(ws + (size_t)B2 * K2 * 4);
    float* ls     = t3 + B2;
    float* rowc   = ls + B2;
    float* colc2  = rowc + B2;
    float* rowsum = colc2 + B2;

    prep_rows<<<dim3(B2), dim3(256), 0, stream>>>(feat, sig, Ahat, Bhat, t3, ls, rowsum);
    prep_pos<<<dim3(B2), dim3(256), 0, stream>>>(feat, sig, label, t3, ls, rowc, colc2);
    gemm_epilogue<<<dim3(4096), dim3(256), 0, stream>>>(Ahat, Bhat, rowc, colc2, rowsum, out);
    loss_k<<<dim3(1), dim3(256), 0, stream>>>(rowsum, out);
}

// Round 2
// 526.556 us; speedup vs baseline: 1.2498x; 1.2498x over previous
//
#include <hip/hip_runtime.h>
#include <hip/hip_bf16.h>
#include <stdint.h>

#define B2 8192
#define D  512
#define K2 1024        // [hi(x^2) | hi(x)] vs [inv | -2x*inv], single fp16 product
#define NM1 (B2 - 1)   // 8191

typedef _Float16 f16;
typedef _Float16 f16x2 __attribute__((ext_vector_type(2)));
typedef _Float16 f16x8 __attribute__((ext_vector_type(8)));
typedef float    f32x4 __attribute__((ext_vector_type(4)));

// ---------------------------------------------------------------------------
// prep (fused): per row i (one block), build fp16 GEMM operands, plus
//   rowc[i]  = 0.1*gt[i] + 0.5*ls[i]          (gt computed exactly in fp32)
//   colc2[i] = -0.5*ls[pos(i)] - 0.1*t3[i]
//   rowsum[i] = 0
// A row: [h(x^2) | h(x)]   B row: [h(inv) | h(-2x*inv)]
// Each thread handles d = 2t, 2t+1 (D = 512 = 2*256): float2 loads, f16x2 stores.
// ---------------------------------------------------------------------------
__global__ __launch_bounds__(256) void prep(
    const float* __restrict__ feat, const float* __restrict__ sig,
    const int* __restrict__ label,
    f16* __restrict__ Ahat, f16* __restrict__ Bhat,
    float* __restrict__ rowc, float* __restrict__ colc2, float* __restrict__ rowsum)
{
    int i = blockIdx.x;
    int t = threadIdx.x;
    int lb = label[i];
    int p  = lb + (lb >= i ? 1 : 0);

    const float2 xv  = ((const float2*)(feat + (size_t)i * D))[t];
    const float2 sv  = ((const float2*)(sig  + (size_t)i * D))[t];
    const float2 xpv = ((const float2*)(feat + (size_t)p * D))[t];
    const float2 spv = ((const float2*)(sig  + (size_t)p * D))[t];

    float inv0 = 1.0f / sv.x, inv1 = 1.0f / sv.y;
    float x20 = xv.x * xv.x, x21 = xv.y * xv.y;

    f16* Ar = Ahat + (size_t)i * K2;
    f16* Br = Bhat + (size_t)i * K2;
    *(f16x2*)&Ar[2 * t]       = f16x2{(f16)x20, (f16)x21};
    *(f16x2*)&Ar[512 + 2 * t] = f16x2{(f16)xv.x, (f16)xv.y};
    *(f16x2*)&Br[2 * t]       = f16x2{(f16)inv0, (f16)inv1};
    *(f16x2*)&Br[512 + 2 * t] = f16x2{(f16)(-2.0f * xv.x * inv0), (f16)(-2.0f * xv.y * inv1)};

    float t3p = x20 * inv0 + x21 * inv1;
    float lsp = __logf(sv.x) + __logf(sv.y);
    float lpp = __logf(spv.x) + __logf(spv.y);
    float dx0 = xv.x - xpv.x, dx1 = xv.y - xpv.y;
    float gtp = dx0 * dx0 / spv.x + dx1 * dx1 / spv.y;

    for (int off = 32; off; off >>= 1) {
        t3p += __shfl_down(t3p, off);
        lsp += __shfl_down(lsp, off);
        lpp += __shfl_down(lpp, off);
        gtp += __shfl_down(gtp, off);
    }
    __shared__ float w0[4], w1[4], w2[4], w3[4];
    int lane = t & 63, w = t >> 6;
    if (lane == 0) { w0[w] = t3p; w1[w] = lsp; w2[w] = lpp; w3[w] = gtp; }
    __syncthreads();
    if (t == 0) {
        float t3 = w0[0] + w0[1] + w0[2] + w0[3];
        float ls = w1[0] + w1[1] + w1[2] + w1[3];
        float lp = w2[0] + w2[1] + w2[2] + w2[3];
        float gt = w3[0] + w3[1] + w3[2] + w3[3];
        rowc[i]  = 0.1f * gt + 0.5f * ls;
        colc2[i] = -0.5f * lp - 0.1f * t3;
        rowsum[i] = 0.0f;
    }
}

// ---------------------------------------------------------------------------
// Fused GEMM (M=N=8192, K=1024, fp16 MFMA 16x16x32) + exp epilogue + row sums.
// 128x128 tile / block, 4 waves in 2x2, each wave 4x4 MFMA tiles.
// BK=64, global_load_lds dwordx4 staging, XOR chunk swizzle (16B chunks).
// ---------------------------------------------------------------------------
__global__ __launch_bounds__(256, 4) void gemm_epilogue(
    const f16* __restrict__ Ahat, const f16* __restrict__ Bhat,
    const float* __restrict__ rowc, const float* __restrict__ colc2,
    float* __restrict__ rowsum, float* __restrict__ out)
{
    __shared__ f16 As[128 * 64];
    __shared__ f16 Bs[128 * 64];
    __shared__ float rS[128], cS[128];

    // swizzle: 8-column panels of the 64x64 block grid
    int bid = blockIdx.x;
    int bn = ((bid >> 9) << 3) + (bid & 7);
    int bm = (bid >> 3) & 63;

    int t = threadIdx.x;
    int l = t & 63, w = t >> 6;
    int wm = (w & 1) * 64, wn = (w >> 1) * 64;

    // staging: thread t covers tile row (t>>3)+32*round, LDS chunk t&7.
    // LDS slot (r, cl) holds global chunk cl ^ (r&7).
    int srow   = t >> 3;                  // 0..31
    int schunk = t & 7;
    int gchunk = schunk ^ (srow & 7);
    const f16* gA = Ahat + (size_t)(bm * 128 + srow) * K2 + gchunk * 8;
    const f16* gB = Bhat + (size_t)(bn * 128 + srow) * K2 + gchunk * 8;

    f32x4 zero4 = {0.f, 0.f, 0.f, 0.f};
    f32x4 acc[4][4];
    #pragma unroll
    for (int a = 0; a < 4; ++a)
        #pragma unroll
        for (int b = 0; b < 4; ++b) acc[a][b] = zero4;

    for (int kb = 0; kb < K2; kb += 64) {
        __syncthreads();   // previous tile fully consumed
        #pragma unroll
        for (int rd = 0; rd < 4; ++rd) {
            __builtin_amdgcn_global_load_lds(
                (const __attribute__((address_space(1))) unsigned int*)(gA + (size_t)rd * 32 * K2 + kb),
                (__attribute__((address_space(3))) unsigned int*)(&As[rd * 2048 + w * 512]),
                16, 0, 0);
            __builtin_amdgcn_global_load_lds(
                (const __attribute__((address_space(1))) unsigned int*)(gB + (size_t)rd * 32 * K2 + kb),
                (__attribute__((address_space(3))) unsigned int*)(&Bs[rd * 2048 + w * 512]),
                16, 0, 0);
        }
        __syncthreads();   // compiler drains vmcnt before barrier

        #pragma unroll
        for (int ks = 0; ks < 2; ++ks) {
            f16x8 af[4], bf[4];
            int cl = (ks * 4 + (l >> 4)) ^ (l & 7);   // swizzled chunk
            #pragma unroll
            for (int mi = 0; mi < 4; ++mi) {
                int ra = wm + mi * 16 + (l & 15);
                af[mi] = *(const f16x8*)&As[ra * 64 + cl * 8];
                int rb = wn + mi * 16 + (l & 15);
                bf[mi] = *(const f16x8*)&Bs[rb * 64 + cl * 8];
            }
            #pragma unroll
            for (int mi = 0; mi < 4; ++mi)
                #pragma unroll
                for (int ni = 0; ni < 4; ++ni)
                    acc[mi][ni] = __builtin_amdgcn_mfma_f32_16x16x32_f16(
                        af[mi], bf[ni], acc[mi][ni], 0, 0, 0);
        }
    }

    // stage per-row/per-col constants
    if (t < 128)      rS[t]       = rowc[bm * 128 + t];
    else              cS[t - 128] = colc2[bn * 128 + (t - 128)];
    __syncthreads();

    int quad = l >> 4, lc = l & 15;
    #pragma unroll
    for (int mi = 0; mi < 4; ++mi) {
        #pragma unroll
        for (int rg = 0; rg < 4; ++rg) {
            int il = wm + mi * 16 + quad * 4 + rg;   // C/D: row = quad*4+reg
            int i  = bm * 128 + il;
            float rc = rS[il];
            float part = 0.f;
            #pragma unroll
            for (int ni = 0; ni < 4; ++ni) {
                int jl = wn + ni * 16 + lc;          // C/D: col = lane&15
                int j  = bn * 128 + jl;
                float v = __expf(rc - 0.1f * acc[mi][ni][rg] + cS[jl]);
                if (j != i) {
                    out[1 + (size_t)i * NM1 + (j - (j > i ? 1 : 0))] = v;
                    part += v;
                }
            }
            // reduce over the 16 lanes holding this row's columns
            part += __shfl_xor(part, 1);
            part += __shfl_xor(part, 2);
            part += __shfl_xor(part, 4);
            part += __shfl_xor(part, 8);
            if (lc == 0) atomicAdd(&rowsum[i], part);
        }
    }
}

// ---------------------------------------------------------------------------
// loss = mean_i log(rowsum[i]) -> out[0]
// ---------------------------------------------------------------------------
__global__ __launch_bounds__(256) void loss_k(const float* __restrict__ rowsum,
                                              float* __restrict__ out)
{
    int t = threadIdx.x;
    float s = 0.f;
    for (int r = t; r < B2; r += 256) s += __logf(rowsum[r]);
    for (int off = 32; off; off >>= 1) s += __shfl_down(s, off);
    __shared__ float wv[4];
    if ((t & 63) == 0) wv[t >> 6] = s;
    __syncthreads();
    if (t == 0) out[0] = (wv[0] + wv[1] + wv[2] + wv[3]) * (1.0f / (float)B2);
}

extern "C" void kernel_launch(void* const* d_in, const int* in_sizes, int n_in,
                              void* d_out, int out_size, void* d_ws, size_t ws_size,
                              hipStream_t stream) {
    const float* feat  = (const float*)d_in[0];
    const float* sig   = (const float*)d_in[1];
    const int*   label = (const int*)d_in[2];
    float* out = (float*)d_out;

    char* ws = (char*)d_ws;
    f16* Ahat = (f16*)ws;                                  // 16 MB
    f16* Bhat = (f16*)(ws + (size_t)B2 * K2 * 2);          // 16 MB
    float* rowc   = (float*)(ws + (size_t)B2 * K2 * 4);
    float* colc2  = rowc + B2;
    float* rowsum = colc2 + B2;

    prep<<<dim3(B2), dim3(256), 0, stream>>>(feat, sig, label, Ahat, Bhat, rowc, colc2, rowsum);
    gemm_epilogue<<<dim3(4096), dim3(256), 0, stream>>>(Ahat, Bhat, rowc, colc2, rowsum, out);
    loss_k<<<dim3(1), dim3(256), 0, stream>>>(rowsum, out);
}